// Round 3
// baseline (317.039 us; speedup 1.0000x reference)
//
#include <hip/hip_runtime.h>

// ---------------- types ----------------
typedef __bf16 bf16x8 __attribute__((ext_vector_type(8)));
typedef __bf16 bf16x4 __attribute__((ext_vector_type(4)));
typedef float  f32x4  __attribute__((ext_vector_type(4)));
typedef short  s16x4  __attribute__((ext_vector_type(4)));

#define AS1 __attribute__((address_space(1)))
#define AS3 __attribute__((address_space(3)))

__device__ inline void gload_lds16(const void* g, void* l) {
  __builtin_amdgcn_global_load_lds((AS1 void*)(g), (AS3 void*)(l), 16, 0, 0);
}

#if __has_builtin(__builtin_amdgcn_exp2f)
#define EXP2(x) __builtin_amdgcn_exp2f(x)
#else
#define EXP2(x) exp2f(x)
#endif

#if __has_builtin(__builtin_amdgcn_mfma_f32_16x16x16bf16_1k)
#define PV_K16 1
#define MFMA16(a, b, c) __builtin_amdgcn_mfma_f32_16x16x16bf16_1k(a, b, c, 0, 0, 0)
#else
#define PV_K16 0
#endif

__device__ inline short bf2s(__bf16 x) {
  union { __bf16 b; short s; } u; u.b = x; return u.s;
}

// ---------------- constants ----------------
#define CB 2
#define CS 2048
#define CE 1024
#define CH 16
#define CD 64
#define GM 4096
#define GN 1024
#define GK 1024

// Q pre-scale: (1/sqrt(H)) * log2(e) so attn uses exp2 directly.
#define QSCALE 0.36067376022224087f

// workspace element offsets (__bf16 units)
#define WS_WQ  0
#define WS_WK  1048576
#define WS_WV  2097152
#define WS_WO  3145728
#define WS_XQ  4194304
#define WS_XK  8388608
#define WS_XV  12582912
#define WS_QH  16777216
#define WS_KH  20971520
#define WS_VT  25165824
#define WS_AO  WS_XQ   // Xq dead when attention writes AO

// ---------------- fp32 -> bf16 conversion (8 elems/thread, 16B stores) ----
__global__ __launch_bounds__(256) void convert_all(
    const float* __restrict__ q, const float* __restrict__ k, const float* __restrict__ v,
    const float* __restrict__ wq, const float* __restrict__ wk,
    const float* __restrict__ wv, const float* __restrict__ wo,
    __bf16* __restrict__ ws) {
  long idx = ((long)blockIdx.x * 256 + threadIdx.x) * 8;
  const float* src;
  __bf16* dst;
  if (idx < 12582912) {
    int a = (int)(idx >> 22);
    long within = idx & 4194303;
    src = (a == 0 ? q : (a == 1 ? k : v)) + within;
    dst = ws + WS_XQ + (long)a * 4194304 + within;
  } else {
    long widx = idx - 12582912;
    int a = (int)(widx >> 20);
    long within = widx & 1048575;
    src = (a == 0 ? wq : (a == 1 ? wk : (a == 2 ? wv : wo))) + within;
    dst = ws + widx;
  }
  float4 f0 = *(const float4*)src;
  float4 f1 = *(const float4*)(src + 4);
  bf16x8 o;
  o[0] = (__bf16)f0.x; o[1] = (__bf16)f0.y; o[2] = (__bf16)f0.z; o[3] = (__bf16)f0.w;
  o[4] = (__bf16)f1.x; o[5] = (__bf16)f1.y; o[6] = (__bf16)f1.z; o[7] = (__bf16)f1.w;
  *(bf16x8*)dst = o;
}

// ======== BK=64 GEMM core with XOR-swizzled LDS (R4, conflict-free) ========
// Bijective XCD-aware blockIdx swizzle (T1): each XCD owns a contiguous chunk
// of tile-space (A-row panels + B fit its 4MB L2). nwg=256, %8==0. Kept from
// R2 (GEMM-side improved ~6us with it).
#define GEMM_BK64_BODY(A_PTR, B_PTR, KLEN)                                          \
  __shared__ __bf16 As[8192];                                                       \
  __shared__ __bf16 Bs[8192];                                                       \
  const int tid = threadIdx.x;                                                      \
  const int w = tid >> 6, l = tid & 63;                                             \
  const int wm = w >> 1, wn = w & 1;                                                \
  const int orig = blockIdx.y * gridDim.x + blockIdx.x;                             \
  const int cpx = (gridDim.x * gridDim.y) >> 3;                                     \
  const int wgid = (orig & 7) * cpx + (orig >> 3);                                  \
  const int bm = (wgid / gridDim.x) * 128, bn = (wgid % gridDim.x) * 128;           \
  const int lr = l & 15, lq = l >> 4;                                               \
  f32x4 acc[4][4] = {};                                                             \
  const int srow = w * 8 + (l >> 3);                                                \
  const int scol = ((l & 7) ^ ((l >> 3) & 7)) * 8;                                  \
  const __bf16* ga0 = (A_PTR) + (size_t)(bm + srow) * GK + scol;                    \
  const __bf16* gb0 = (B_PTR) + (size_t)(bn + srow) * GK + scol;                    \
  const int dstg = w * 64 + l;                                                      \
  for (int k0 = 0; k0 < (KLEN); k0 += 64) {                                         \
    __syncthreads();                                                                \
    for (int i = 0; i < 4; i++) {                                                   \
      gload_lds16(ga0 + (size_t)(i * 32) * GK + k0, &As[(i * 256 + dstg) * 8]);     \
      gload_lds16(gb0 + (size_t)(i * 32) * GK + k0, &Bs[(i * 256 + dstg) * 8]);     \
    }                                                                               \
    __syncthreads();                                                                \
    for (int kk = 0; kk < 2; kk++) {                                                \
      bf16x8 af[4], bfr[4];                                                         \
      for (int mi = 0; mi < 4; mi++) {                                              \
        const int row = wm * 64 + mi * 16 + lr;                                     \
        af[mi] = *(const bf16x8*)&As[(row * 8 + ((kk * 4 + lq) ^ (row & 7))) * 8];  \
      }                                                                             \
      for (int ni = 0; ni < 4; ni++) {                                              \
        const int row = wn * 64 + ni * 16 + lr;                                     \
        bfr[ni] = *(const bf16x8*)&Bs[(row * 8 + ((kk * 4 + lq) ^ (row & 7))) * 8]; \
      }                                                                             \
      for (int mi = 0; mi < 4; mi++)                                                \
        for (int ni = 0; ni < 4; ni++)                                              \
          acc[mi][ni] = __builtin_amdgcn_mfma_f32_16x16x32_bf16(af[mi], bfr[ni],    \
                                                                acc[mi][ni], 0, 0, 0); \
    }                                                                               \
  }

// ---------------- fused QKV GEMM: grid (8, 32, 3) ----------------
__global__ __launch_bounds__(256) void qkv_gemm(
    const __bf16* __restrict__ Xq, const __bf16* __restrict__ Xk, const __bf16* __restrict__ Xv,
    const __bf16* __restrict__ Wq, const __bf16* __restrict__ Wk, const __bf16* __restrict__ Wv,
    const float* __restrict__ bq, const float* __restrict__ bk, const float* __restrict__ bv,
    __bf16* __restrict__ Qh, __bf16* __restrict__ Kh, __bf16* __restrict__ Vt) {
  const int mode = blockIdx.z;
  const __bf16* A  = mode == 0 ? Xq : (mode == 1 ? Xk : Xv);
  const __bf16* Bw = mode == 0 ? Wq : (mode == 1 ? Wk : Wv);
  const float* bias = mode == 0 ? bq : (mode == 1 ? bk : bv);

  GEMM_BK64_BODY(A, Bw, GK)

  const int row0 = bm + wm * 64;
  const int col0 = bn + wn * 64;
  for (int ni = 0; ni < 4; ni++) {
    const int col = col0 + ni * 16 + lr;
    const float bb = bias[col];
    for (int mi = 0; mi < 4; mi++) {
      const int row = row0 + mi * 16 + lq * 4;
      if (mode == 0) {
        for (int r = 0; r < 4; r++)
          Qh[(size_t)(row + r) * GN + col] = (__bf16)((acc[mi][ni][r] + bb) * QSCALE);
      } else if (mode == 1) {
        for (int r = 0; r < 4; r++)
          Kh[(size_t)(row + r) * GN + col] = (__bf16)(acc[mi][ni][r] + bb);
      } else {
        const int b = row >> 11, s = row & 2047;
        const int h = col >> 6, d = col & 63;
        bf16x4 pk;
        for (int r = 0; r < 4; r++) pk[r] = (__bf16)(acc[mi][ni][r] + bb);
        *(bf16x4*)&Vt[(size_t)((b * CH + h) * CD + d) * CS + s] = pk;
      }
    }
  }
}

// ---------------- Wo GEMM: grid (8, 32), direct store (no atomics) --------
__global__ __launch_bounds__(256) void gemm_wo(const __bf16* __restrict__ Ain,
                                               const __bf16* __restrict__ Bw,
                                               const float* __restrict__ bias,
                                               float* __restrict__ O) {
  GEMM_BK64_BODY(Ain, Bw, GK)

  const int row0 = bm + wm * 64;
  const int col0 = bn + wn * 64;
  for (int ni = 0; ni < 4; ni++) {
    const int col = col0 + ni * 16 + lr;
    const float bb = bias[col];
    for (int mi = 0; mi < 4; mi++) {
      const int row = row0 + mi * 16 + lq * 4;
      for (int r = 0; r < 4; r++)
        O[(size_t)(row + r) * GN + col] = acc[mi][ni][r] + bb;
    }
  }
}

// ---------------- fused flash attention v9 ----------------
// v6 compute shape exactly (4 waves x 32 q-rows, R0-verified 59us), with the
// staging granularity doubled: 256 keys staged per barrier pair, processed
// as two 128-key chunks between the SAME two barriers. Halves the per-block
// drain events (16 -> 8) and lets the compiler interleave PV(chunk0) with
// QK(chunk1) — both chunks are LDS-resident, static indices, no extra
// barriers (excludes R1's failure modes). LDS 64KB -> 2 blocks/CU, which is
// what the 512-block grid gives anyway; VGPR headroom to ~256 at 2 w/SIMD.
__global__ __launch_bounds__(256, 2) void attn(const __bf16* __restrict__ Qh,
                                               const __bf16* __restrict__ Kh,
                                               const __bf16* __restrict__ Vt,
                                               __bf16* __restrict__ AO) {
  // Ks[c]: [dchunk j 0..7][keyslot 0..127][8], keyslot = key ^ (2*(j&3))
  // Vs[c]: [keychunk j2 0..15][dslot 0..63][8], dslot = d ^ (4*(j2&1))
  __shared__ __bf16 Ks[2][8192];
  __shared__ __bf16 Vs[2][8192];

  const int tid = threadIdx.x, w = tid >> 6, l = tid & 63;
  const int lr = l & 15, lq = l >> 4;
  const int bh = blockIdx.x;
  const int b = bh >> 4, h = bh & 15;
  const int q0 = blockIdx.y * 128 + w * 32;

  // Q as B-operand: B[n=q][k=d=kk*32+lq*8+j]  (Qh pre-scaled by QSCALE)
  bf16x8 qf[2][2];
  for (int mi = 0; mi < 2; mi++)
    for (int kk = 0; kk < 2; kk++)
      qf[mi][kk] = *(const bf16x8*)&Qh[((size_t)b * CS + q0 + mi * 16 + lr) * CE + h * CD + kk * 32 + lq * 8];

  f32x4 o[2][4] = {};
  float lsum[2] = {0.f, 0.f};
#if !PV_K16
  const bool hi_half = (lq & 1);
#endif

  for (int kt = 0; kt < CS / 256; kt++) {
    __syncthreads();
    // stage both 128-key chunks (R3-verified layout per chunk)
    for (int c = 0; c < 2; c++) {
      const int keybase = kt * 256 + c * 128;
      for (int i = 0; i < 4; i++) {
        const int j = w * 2 + (i >> 1), hf = i & 1;
        const int key = (hf * 64 + l) ^ ((j & 3) * 2);
        gload_lds16(&Kh[((size_t)b * CS + keybase + key) * CE + h * CD + j * 8],
                    &Ks[c][(j * 128 + hf * 64) * 8]);
      }
      for (int i = 0; i < 4; i++) {
        const int j2 = w * 4 + i;
        const int d = l ^ ((j2 & 1) * 4);
        gload_lds16(&Vt[((size_t)bh * CD + d) * CS + keybase + j2 * 8],
                    &Vs[c][(j2 * 64) * 8]);
      }
    }
    __syncthreads();  // drains vmcnt: both chunks LDS-resident

    for (int c = 0; c < 2; c++) {
      // S^T = K.Q^T : sa[mi][ni][r] <-> key = ni*16+lq*4+r, q = q0+mi*16+lr
      f32x4 sa[2][8] = {};
      for (int kk = 0; kk < 2; kk++) {
        bf16x8 kf[8];
        for (int ni = 0; ni < 8; ni++)
          kf[ni] = *(const bf16x8*)&Ks[c][((kk * 4 + lq) * 128 + ((ni * 16 + lr) ^ (lq * 2))) * 8];
        for (int mi = 0; mi < 2; mi++)
          for (int ni = 0; ni < 8; ni++)
            sa[mi][ni] = __builtin_amdgcn_mfma_f32_16x16x32_bf16(kf[ni], qf[mi][kk], sa[mi][ni], 0, 0, 0);
      }

#if PV_K16
      // exp2 + direct K=16 A-frag; V b64 frags shared across both q-halves
      for (int ni = 0; ni < 8; ni++) {
        s16x4 pa4[2];
        for (int mi = 0; mi < 2; mi++)
          for (int r = 0; r < 4; r++) {
            const float p = EXP2(sa[mi][ni][r]);
            lsum[mi] += p;
            pa4[mi][r] = bf2s((__bf16)p);
          }
        const int j2 = ni * 2 + (lq >> 1);
        const int base = j2 * 64;
        const int sw = (j2 & 1) * 4;
        for (int di = 0; di < 4; di++) {
          const int dslot = (di * 16 + lr) ^ sw;
          const s16x4 vb4 = *(const s16x4*)&Vs[c][(base + dslot) * 8 + (lq & 1) * 4];
          for (int mi = 0; mi < 2; mi++)
            o[mi][di] = MFMA16(pa4[mi], vb4, o[mi][di]);
        }
      }
#else
      // fallback: zero-padded K=32 PV
      for (int ni = 0; ni < 8; ni++) {
        bf16x8 pa[2];
        for (int mi = 0; mi < 2; mi++) {
          bf16x8 f;
          for (int r = 0; r < 4; r++) {
            const float p = EXP2(sa[mi][ni][r]);
            lsum[mi] += p;
            const __bf16 bv2 = (__bf16)p;
            f[r]     = hi_half ? (__bf16)0.f : bv2;
            f[4 + r] = hi_half ? bv2 : (__bf16)0.f;
          }
          pa[mi] = f;
        }
        for (int di = 0; di < 4; di++) {
          const bf16x8 vbf = *(const bf16x8*)&Vs[c][((ni * 2 + (lq >> 1)) * 64 + ((di * 16 + lr) ^ ((lq >> 1) * 4))) * 8];
          for (int mi = 0; mi < 2; mi++)
            o[mi][di] = __builtin_amdgcn_mfma_f32_16x16x32_bf16(pa[mi], vbf, o[mi][di], 0, 0, 0);
        }
      }
#endif
    }
  }

  // deferred row-sum: lane partial for q = q0+mi*16+lr over keys {16ni+lq*4+r}
  for (int mi = 0; mi < 2; mi++) {
    lsum[mi] += __shfl_xor(lsum[mi], 16, 64);
    lsum[mi] += __shfl_xor(lsum[mi], 32, 64);
  }

  // o C-layout: row q_local = lq*4+r, col d = di*16+lr
  for (int mi = 0; mi < 2; mi++) {
    f32x4 rv;
    for (int r = 0; r < 4; r++) rv[r] = 1.0f / __shfl(lsum[mi], lq * 4 + r, 64);
    for (int di = 0; di < 4; di++)
      for (int r = 0; r < 4; r++) {
        const size_t s = q0 + mi * 16 + lq * 4 + r;
        AO[((size_t)b * CS + s) * CE + h * CD + di * 16 + lr] = (__bf16)(o[mi][di][r] * rv[r]);
      }
  }
}

// ---------------- launch ----------------
extern "C" void kernel_launch(void* const* d_in, const int* in_sizes, int n_in,
                              void* d_out, int out_size, void* d_ws, size_t ws_size,
                              hipStream_t stream) {
  (void)in_sizes; (void)n_in; (void)out_size; (void)ws_size;
  const float* q  = (const float*)d_in[0];
  const float* k  = (const float*)d_in[1];
  const float* v  = (const float*)d_in[2];
  const float* Wq = (const float*)d_in[3];
  const float* bq = (const float*)d_in[4];
  const float* Wk = (const float*)d_in[5];
  const float* bk = (const float*)d_in[6];
  const float* Wv = (const float*)d_in[7];
  const float* bv = (const float*)d_in[8];
  const float* Wo = (const float*)d_in[9];
  const float* bo = (const float*)d_in[10];

  __bf16* ws = (__bf16*)d_ws;
  __bf16 *Wq_b = ws + WS_WQ, *Wk_b = ws + WS_WK, *Wv_b = ws + WS_WV, *Wo_b = ws + WS_WO;
  __bf16 *Xq = ws + WS_XQ, *Xk = ws + WS_XK, *Xv = ws + WS_XV;
  __bf16 *Qh = ws + WS_QH, *Kh = ws + WS_KH, *Vt = ws + WS_VT;
  __bf16 *AO = ws + WS_AO;

  convert_all<<<8192, 256, 0, stream>>>(q, k, v, Wq, Wk, Wv, Wo, ws);

  qkv_gemm<<<dim3(GN / 128, GM / 128, 3), 256, 0, stream>>>(
      Xq, Xk, Xv, Wq_b, Wk_b, Wv_b, bq, bk, bv, Qh, Kh, Vt);

  attn<<<dim3(CB * CH, CS / 128), 256, 0, stream>>>(Qh, Kh, Vt, AO);

  gemm_wo<<<dim3(GN / 128, GM / 128), 256, 0, stream>>>(AO, Wo_b, bo, (float*)d_out);
}

// Round 5
// 225.323 us; speedup vs baseline: 1.4070x; 1.4070x over previous
//
#include <hip/hip_runtime.h>

// ---------------- types ----------------
typedef __bf16 bf16x8 __attribute__((ext_vector_type(8)));
typedef __bf16 bf16x4 __attribute__((ext_vector_type(4)));
typedef float  f32x4  __attribute__((ext_vector_type(4)));
typedef short  s16x4  __attribute__((ext_vector_type(4)));

#define AS1 __attribute__((address_space(1)))
#define AS3 __attribute__((address_space(3)))

__device__ inline void gload_lds16(const void* g, void* l) {
  __builtin_amdgcn_global_load_lds((AS1 void*)(g), (AS3 void*)(l), 16, 0, 0);
}

#if __has_builtin(__builtin_amdgcn_exp2f)
#define EXP2(x) __builtin_amdgcn_exp2f(x)
#else
#define EXP2(x) exp2f(x)
#endif

#if __has_builtin(__builtin_amdgcn_mfma_f32_16x16x16bf16_1k)
#define PV_K16 1
#define MFMA16(a, b, c) __builtin_amdgcn_mfma_f32_16x16x16bf16_1k(a, b, c, 0, 0, 0)
#else
#define PV_K16 0
#endif

__device__ inline short bf2s(__bf16 x) {
  union { __bf16 b; short s; } u; u.b = x; return u.s;
}

// ---------------- constants ----------------
#define CB 2
#define CS 2048
#define CE 1024
#define CH 16
#define CD 64
#define GM 4096
#define GN 1024
#define GK 1024

// Q pre-scale: (1/sqrt(H)) * log2(e) so attn uses exp2 directly.
#define QSCALE 0.36067376022224087f

// workspace element offsets (__bf16 units)
#define WS_WQ  0
#define WS_WK  1048576
#define WS_WV  2097152
#define WS_WO  3145728
#define WS_XQ  4194304
#define WS_XK  8388608
#define WS_XV  12582912
#define WS_QH  16777216
#define WS_KH  20971520
#define WS_VT  25165824
#define WS_AO  WS_XQ   // Xq dead when attention writes AO

// ---------------- fp32 -> bf16 conversion (8 elems/thread, 16B stores) ----
__global__ __launch_bounds__(256) void convert_all(
    const float* __restrict__ q, const float* __restrict__ k, const float* __restrict__ v,
    const float* __restrict__ wq, const float* __restrict__ wk,
    const float* __restrict__ wv, const float* __restrict__ wo,
    __bf16* __restrict__ ws) {
  long idx = ((long)blockIdx.x * 256 + threadIdx.x) * 8;
  const float* src;
  __bf16* dst;
  if (idx < 12582912) {
    int a = (int)(idx >> 22);
    long within = idx & 4194303;
    src = (a == 0 ? q : (a == 1 ? k : v)) + within;
    dst = ws + WS_XQ + (long)a * 4194304 + within;
  } else {
    long widx = idx - 12582912;
    int a = (int)(widx >> 20);
    long within = widx & 1048575;
    src = (a == 0 ? wq : (a == 1 ? wk : (a == 2 ? wv : wo))) + within;
    dst = ws + widx;
  }
  float4 f0 = *(const float4*)src;
  float4 f1 = *(const float4*)(src + 4);
  bf16x8 o;
  o[0] = (__bf16)f0.x; o[1] = (__bf16)f0.y; o[2] = (__bf16)f0.z; o[3] = (__bf16)f0.w;
  o[4] = (__bf16)f1.x; o[5] = (__bf16)f1.y; o[6] = (__bf16)f1.z; o[7] = (__bf16)f1.w;
  *(bf16x8*)dst = o;
}

// ======== BK=64 GEMM core with XOR-swizzled LDS (R4, conflict-free) ========
// Bijective XCD-aware blockIdx swizzle (T1): each XCD owns a contiguous chunk
// of tile-space (A-row panels + full 2MB B fit its 4MB L2). nwg=256, %8==0.
// Kept from R2: GEMM-side 170.2 -> 164.4us with this as the only change.
#define GEMM_BK64_BODY(A_PTR, B_PTR, KLEN)                                          \
  __shared__ __bf16 As[8192];                                                       \
  __shared__ __bf16 Bs[8192];                                                       \
  const int tid = threadIdx.x;                                                      \
  const int w = tid >> 6, l = tid & 63;                                             \
  const int wm = w >> 1, wn = w & 1;                                                \
  const int orig = blockIdx.y * gridDim.x + blockIdx.x;                             \
  const int cpx = (gridDim.x * gridDim.y) >> 3;                                     \
  const int wgid = (orig & 7) * cpx + (orig >> 3);                                  \
  const int bm = (wgid / gridDim.x) * 128, bn = (wgid % gridDim.x) * 128;           \
  const int lr = l & 15, lq = l >> 4;                                               \
  f32x4 acc[4][4] = {};                                                             \
  const int srow = w * 8 + (l >> 3);                                                \
  const int scol = ((l & 7) ^ ((l >> 3) & 7)) * 8;                                  \
  const __bf16* ga0 = (A_PTR) + (size_t)(bm + srow) * GK + scol;                    \
  const __bf16* gb0 = (B_PTR) + (size_t)(bn + srow) * GK + scol;                    \
  const int dstg = w * 64 + l;                                                      \
  for (int k0 = 0; k0 < (KLEN); k0 += 64) {                                         \
    __syncthreads();                                                                \
    for (int i = 0; i < 4; i++) {                                                   \
      gload_lds16(ga0 + (size_t)(i * 32) * GK + k0, &As[(i * 256 + dstg) * 8]);     \
      gload_lds16(gb0 + (size_t)(i * 32) * GK + k0, &Bs[(i * 256 + dstg) * 8]);     \
    }                                                                               \
    __syncthreads();                                                                \
    for (int kk = 0; kk < 2; kk++) {                                                \
      bf16x8 af[4], bfr[4];                                                         \
      for (int mi = 0; mi < 4; mi++) {                                              \
        const int row = wm * 64 + mi * 16 + lr;                                     \
        af[mi] = *(const bf16x8*)&As[(row * 8 + ((kk * 4 + lq) ^ (row & 7))) * 8];  \
      }                                                                             \
      for (int ni = 0; ni < 4; ni++) {                                              \
        const int row = wn * 64 + ni * 16 + lr;                                     \
        bfr[ni] = *(const bf16x8*)&Bs[(row * 8 + ((kk * 4 + lq) ^ (row & 7))) * 8]; \
      }                                                                             \
      for (int mi = 0; mi < 4; mi++)                                                \
        for (int ni = 0; ni < 4; ni++)                                              \
          acc[mi][ni] = __builtin_amdgcn_mfma_f32_16x16x32_bf16(af[mi], bfr[ni],    \
                                                                acc[mi][ni], 0, 0, 0); \
    }                                                                               \
  }

// ---------------- fused QKV GEMM: grid (8, 32, 3) ----------------
__global__ __launch_bounds__(256) void qkv_gemm(
    const __bf16* __restrict__ Xq, const __bf16* __restrict__ Xk, const __bf16* __restrict__ Xv,
    const __bf16* __restrict__ Wq, const __bf16* __restrict__ Wk, const __bf16* __restrict__ Wv,
    const float* __restrict__ bq, const float* __restrict__ bk, const float* __restrict__ bv,
    __bf16* __restrict__ Qh, __bf16* __restrict__ Kh, __bf16* __restrict__ Vt) {
  const int mode = blockIdx.z;
  const __bf16* A  = mode == 0 ? Xq : (mode == 1 ? Xk : Xv);
  const __bf16* Bw = mode == 0 ? Wq : (mode == 1 ? Wk : Wv);
  const float* bias = mode == 0 ? bq : (mode == 1 ? bk : bv);

  GEMM_BK64_BODY(A, Bw, GK)

  const int row0 = bm + wm * 64;
  const int col0 = bn + wn * 64;
  for (int ni = 0; ni < 4; ni++) {
    const int col = col0 + ni * 16 + lr;
    const float bb = bias[col];
    for (int mi = 0; mi < 4; mi++) {
      const int row = row0 + mi * 16 + lq * 4;
      if (mode == 0) {
        for (int r = 0; r < 4; r++)
          Qh[(size_t)(row + r) * GN + col] = (__bf16)((acc[mi][ni][r] + bb) * QSCALE);
      } else if (mode == 1) {
        for (int r = 0; r < 4; r++)
          Kh[(size_t)(row + r) * GN + col] = (__bf16)(acc[mi][ni][r] + bb);
      } else {
        const int b = row >> 11, s = row & 2047;
        const int h = col >> 6, d = col & 63;
        bf16x4 pk;
        for (int r = 0; r < 4; r++) pk[r] = (__bf16)(acc[mi][ni][r] + bb);
        *(bf16x4*)&Vt[(size_t)((b * CH + h) * CD + d) * CS + s] = pk;
      }
    }
  }
}

// ---------------- Wo GEMM: grid (8, 32), direct store (no atomics) --------
__global__ __launch_bounds__(256) void gemm_wo(const __bf16* __restrict__ Ain,
                                               const __bf16* __restrict__ Bw,
                                               const float* __restrict__ bias,
                                               float* __restrict__ O) {
  GEMM_BK64_BODY(Ain, Bw, GK)

  const int row0 = bm + wm * 64;
  const int col0 = bn + wn * 64;
  for (int ni = 0; ni < 4; ni++) {
    const int col = col0 + ni * 16 + lr;
    const float bb = bias[col];
    for (int mi = 0; mi < 4; mi++) {
      const int row = row0 + mi * 16 + lq * 4;
      for (int r = 0; r < 4; r++)
        O[(size_t)(row + r) * GN + col] = acc[mi][ni][r] + bb;
    }
  }
}

// ---------------- fused flash attention v6 (R0-verified, 59us) ----------
// 256 threads = 4 waves x 32 q-rows, 128-key tiles. S^T = K.Q^T, fast exp2,
// K=16 PV MFMA. Structural experiments R1 (dbuf+counted vmcnt), R2 (16-row
// waves / 4 blocks/CU), R3 (256-key staging) ALL regressed: 70.7 / 90.9 /
// 153.5 us vs this shape's 59.1. Do not re-attempt those axes without new
// counter evidence: R1 = intra-block pipeline adds latency at 4 waves;
// R2 = staging cost is per-block, more blocks = more traffic; R3 = 2-chunk
// live state spills to scratch (FETCH/WRITE +90MB).
__global__ __launch_bounds__(256, 2) void attn(const __bf16* __restrict__ Qh,
                                               const __bf16* __restrict__ Kh,
                                               const __bf16* __restrict__ Vt,
                                               __bf16* __restrict__ AO) {
  // Ks: [dchunk j 0..7][keyslot 0..127][8], keyslot = key ^ (2*(j&3))
  // Vs: [keychunk j2 0..15][dslot 0..63][8], dslot = d ^ (4*(j2&1))
  __shared__ __bf16 Ks[8192];
  __shared__ __bf16 Vs[8192];

  const int tid = threadIdx.x, w = tid >> 6, l = tid & 63;
  const int lr = l & 15, lq = l >> 4;
  const int bh = blockIdx.x;
  const int b = bh >> 4, h = bh & 15;
  const int q0 = blockIdx.y * 128 + w * 32;

  // Q as B-operand: B[n=q][k=d=kk*32+lq*8+j]  (Qh pre-scaled by QSCALE)
  bf16x8 qf[2][2];
  for (int mi = 0; mi < 2; mi++)
    for (int kk = 0; kk < 2; kk++)
      qf[mi][kk] = *(const bf16x8*)&Qh[((size_t)b * CS + q0 + mi * 16 + lr) * CE + h * CD + kk * 32 + lq * 8];

  f32x4 o[2][4] = {};
  float lsum[2] = {0.f, 0.f};
#if !PV_K16
  const bool hi_half = (lq & 1);
#endif

  for (int kt = 0; kt < CS / 128; kt++) {
    __syncthreads();
    // staging (R3-verified): K chunk j = w*2+(i>>1), half = i&1; V keychunk j2
    for (int i = 0; i < 4; i++) {
      const int j = w * 2 + (i >> 1), hf = i & 1;
      const int key = (hf * 64 + l) ^ ((j & 3) * 2);
      gload_lds16(&Kh[((size_t)b * CS + kt * 128 + key) * CE + h * CD + j * 8],
                  &Ks[(j * 128 + hf * 64) * 8]);
    }
    for (int i = 0; i < 4; i++) {
      const int j2 = w * 4 + i;
      const int d = l ^ ((j2 & 1) * 4);
      gload_lds16(&Vt[((size_t)bh * CD + d) * CS + kt * 128 + j2 * 8],
                  &Vs[(j2 * 64) * 8]);
    }
    __syncthreads();

    // S^T = K.Q^T : sa[mi][ni][r] <-> key = ni*16+lq*4+r, q = q0+mi*16+lr
    f32x4 sa[2][8] = {};
    for (int kk = 0; kk < 2; kk++) {
      bf16x8 kf[8];
      for (int ni = 0; ni < 8; ni++)
        kf[ni] = *(const bf16x8*)&Ks[((kk * 4 + lq) * 128 + ((ni * 16 + lr) ^ (lq * 2))) * 8];
      for (int mi = 0; mi < 2; mi++)
        for (int ni = 0; ni < 8; ni++)
          sa[mi][ni] = __builtin_amdgcn_mfma_f32_16x16x32_bf16(kf[ni], qf[mi][kk], sa[mi][ni], 0, 0, 0);
    }

#if PV_K16
    // exp2 + direct K=16 A-frag; V b64 frags shared across both q-halves
    for (int ni = 0; ni < 8; ni++) {
      s16x4 pa4[2];
      for (int mi = 0; mi < 2; mi++)
        for (int r = 0; r < 4; r++) {
          const float p = EXP2(sa[mi][ni][r]);
          lsum[mi] += p;
          pa4[mi][r] = bf2s((__bf16)p);
        }
      const int j2 = ni * 2 + (lq >> 1);
      const int base = j2 * 64;
      const int sw = (j2 & 1) * 4;
      for (int di = 0; di < 4; di++) {
        const int dslot = (di * 16 + lr) ^ sw;
        const s16x4 vb4 = *(const s16x4*)&Vs[(base + dslot) * 8 + (lq & 1) * 4];
        for (int mi = 0; mi < 2; mi++)
          o[mi][di] = MFMA16(pa4[mi], vb4, o[mi][di]);
      }
    }
#else
    // fallback: zero-padded K=32 PV
    for (int ni = 0; ni < 8; ni++) {
      bf16x8 pa[2];
      for (int mi = 0; mi < 2; mi++) {
        bf16x8 f;
        for (int r = 0; r < 4; r++) {
          const float p = EXP2(sa[mi][ni][r]);
          lsum[mi] += p;
          const __bf16 bv2 = (__bf16)p;
          f[r]     = hi_half ? (__bf16)0.f : bv2;
          f[4 + r] = hi_half ? bv2 : (__bf16)0.f;
        }
        pa[mi] = f;
      }
      for (int di = 0; di < 4; di++) {
        const bf16x8 vbf = *(const bf16x8*)&Vs[((ni * 2 + (lq >> 1)) * 64 + ((di * 16 + lr) ^ ((lq >> 1) * 4))) * 8];
        for (int mi = 0; mi < 2; mi++)
          o[mi][di] = __builtin_amdgcn_mfma_f32_16x16x32_bf16(pa[mi], vbf, o[mi][di], 0, 0, 0);
      }
    }
#endif
  }

  // deferred row-sum: lane partial for q = q0+mi*16+lr over keys {16ni+lq*4+r}
  for (int mi = 0; mi < 2; mi++) {
    lsum[mi] += __shfl_xor(lsum[mi], 16, 64);
    lsum[mi] += __shfl_xor(lsum[mi], 32, 64);
  }

  // o C-layout: row q_local = lq*4+r, col d = di*16+lr
  for (int mi = 0; mi < 2; mi++) {
    f32x4 rv;
    for (int r = 0; r < 4; r++) rv[r] = 1.0f / __shfl(lsum[mi], lq * 4 + r, 64);
    for (int di = 0; di < 4; di++)
      for (int r = 0; r < 4; r++) {
        const size_t s = q0 + mi * 16 + lq * 4 + r;
        AO[((size_t)b * CS + s) * CE + h * CD + di * 16 + lr] = (__bf16)(o[mi][di][r] * rv[r]);
      }
  }
}

// ---------------- launch ----------------
extern "C" void kernel_launch(void* const* d_in, const int* in_sizes, int n_in,
                              void* d_out, int out_size, void* d_ws, size_t ws_size,
                              hipStream_t stream) {
  (void)in_sizes; (void)n_in; (void)out_size; (void)ws_size;
  const float* q  = (const float*)d_in[0];
  const float* k  = (const float*)d_in[1];
  const float* v  = (const float*)d_in[2];
  const float* Wq = (const float*)d_in[3];
  const float* bq = (const float*)d_in[4];
  const float* Wk = (const float*)d_in[5];
  const float* bk = (const float*)d_in[6];
  const float* Wv = (const float*)d_in[7];
  const float* bv = (const float*)d_in[8];
  const float* Wo = (const float*)d_in[9];
  const float* bo = (const float*)d_in[10];

  __bf16* ws = (__bf16*)d_ws;
  __bf16 *Wq_b = ws + WS_WQ, *Wk_b = ws + WS_WK, *Wv_b = ws + WS_WV, *Wo_b = ws + WS_WO;
  __bf16 *Xq = ws + WS_XQ, *Xk = ws + WS_XK, *Xv = ws + WS_XV;
  __bf16 *Qh = ws + WS_QH, *Kh = ws + WS_KH, *Vt = ws + WS_VT;
  __bf16 *AO = ws + WS_AO;

  convert_all<<<8192, 256, 0, stream>>>(q, k, v, Wq, Wk, Wv, Wo, ws);

  qkv_gemm<<<dim3(GN / 128, GM / 128, 3), 256, 0, stream>>>(
      Xq, Xk, Xv, Wq_b, Wk_b, Wv_b, bq, bk, bv, Qh, Kh, Vt);

  attn<<<dim3(CB * CH, CS / 128), 256, 0, stream>>>(Qh, Kh, Vt, AO);

  gemm_wo<<<dim3(GN / 128, GM / 128), 256, 0, stream>>>(AO, Wo_b, bo, (float*)d_out);
}

// Round 6
// 221.604 us; speedup vs baseline: 1.4307x; 1.0168x over previous
//
#include <hip/hip_runtime.h>

// ---------------- types ----------------
typedef __bf16 bf16x8 __attribute__((ext_vector_type(8)));
typedef __bf16 bf16x4 __attribute__((ext_vector_type(4)));
typedef float  f32x4  __attribute__((ext_vector_type(4)));
typedef short  s16x4  __attribute__((ext_vector_type(4)));

#define AS1 __attribute__((address_space(1)))
#define AS3 __attribute__((address_space(3)))

__device__ inline void gload_lds16(const void* g, void* l) {
  __builtin_amdgcn_global_load_lds((AS1 void*)(g), (AS3 void*)(l), 16, 0, 0);
}

#if __has_builtin(__builtin_amdgcn_exp2f)
#define EXP2(x) __builtin_amdgcn_exp2f(x)
#else
#define EXP2(x) exp2f(x)
#endif

#if __has_builtin(__builtin_amdgcn_mfma_f32_16x16x16bf16_1k)
#define PV_K16 1
#define MFMA16(a, b, c) __builtin_amdgcn_mfma_f32_16x16x16bf16_1k(a, b, c, 0, 0, 0)
#else
#define PV_K16 0
#endif

__device__ inline short bf2s(__bf16 x) {
  union { __bf16 b; short s; } u; u.b = x; return u.s;
}

// ---------------- constants ----------------
#define CB 2
#define CS 2048
#define CE 1024
#define CH 16
#define CD 64
#define GM 4096
#define GN 1024
#define GK 1024

// Q pre-scale: (1/sqrt(H)) * log2(e) so attn uses exp2 directly.
#define QSCALE 0.36067376022224087f

// workspace element offsets (__bf16 units)
#define WS_WQ  0
#define WS_WK  1048576
#define WS_WV  2097152
#define WS_WO  3145728
#define WS_XQ  4194304
#define WS_XK  8388608
#define WS_XV  12582912
#define WS_QH  16777216
#define WS_KH  20971520
#define WS_VT  25165824
#define WS_AO  WS_XQ   // Xq dead when attention writes AO

// ---------------- fp32 -> bf16 conversion (8 elems/thread, 16B stores) ----
__global__ __launch_bounds__(256) void convert_all(
    const float* __restrict__ q, const float* __restrict__ k, const float* __restrict__ v,
    const float* __restrict__ wq, const float* __restrict__ wk,
    const float* __restrict__ wv, const float* __restrict__ wo,
    __bf16* __restrict__ ws) {
  long idx = ((long)blockIdx.x * 256 + threadIdx.x) * 8;
  const float* src;
  __bf16* dst;
  if (idx < 12582912) {
    int a = (int)(idx >> 22);
    long within = idx & 4194303;
    src = (a == 0 ? q : (a == 1 ? k : v)) + within;
    dst = ws + WS_XQ + (long)a * 4194304 + within;
  } else {
    long widx = idx - 12582912;
    int a = (int)(widx >> 20);
    long within = widx & 1048575;
    src = (a == 0 ? wq : (a == 1 ? wk : (a == 2 ? wv : wo))) + within;
    dst = ws + widx;
  }
  float4 f0 = *(const float4*)src;
  float4 f1 = *(const float4*)(src + 4);
  bf16x8 o;
  o[0] = (__bf16)f0.x; o[1] = (__bf16)f0.y; o[2] = (__bf16)f0.z; o[3] = (__bf16)f0.w;
  o[4] = (__bf16)f1.x; o[5] = (__bf16)f1.y; o[6] = (__bf16)f1.z; o[7] = (__bf16)f1.w;
  *(bf16x8*)dst = o;
}

// ======== BK=64 GEMM core with XOR-swizzled LDS (R4, conflict-free) ========
// Bijective XCD-aware blockIdx swizzle (T1): each XCD owns a contiguous chunk
// of tile-space (A-row panels + full 2MB B fit its 4MB L2). nwg%8==0.
// Verified across R0->R5: non-attn side 170.2 -> ~164-168us with this.
#define GEMM_BK64_BODY(A_PTR, B_PTR, KLEN)                                          \
  __shared__ __bf16 As[8192];                                                       \
  __shared__ __bf16 Bs[8192];                                                       \
  const int tid = threadIdx.x;                                                      \
  const int w = tid >> 6, l = tid & 63;                                             \
  const int wm = w >> 1, wn = w & 1;                                                \
  const int orig = blockIdx.y * gridDim.x + blockIdx.x;                             \
  const int cpx = (gridDim.x * gridDim.y) >> 3;                                     \
  const int wgid = (orig & 7) * cpx + (orig >> 3);                                  \
  const int bm = (wgid / gridDim.x) * 128, bn = (wgid % gridDim.x) * 128;           \
  const int lr = l & 15, lq = l >> 4;                                               \
  f32x4 acc[4][4] = {};                                                             \
  const int srow = w * 8 + (l >> 3);                                                \
  const int scol = ((l & 7) ^ ((l >> 3) & 7)) * 8;                                  \
  const __bf16* ga0 = (A_PTR) + (size_t)(bm + srow) * GK + scol;                    \
  const __bf16* gb0 = (B_PTR) + (size_t)(bn + srow) * GK + scol;                    \
  const int dstg = w * 64 + l;                                                      \
  for (int k0 = 0; k0 < (KLEN); k0 += 64) {                                         \
    __syncthreads();                                                                \
    for (int i = 0; i < 4; i++) {                                                   \
      gload_lds16(ga0 + (size_t)(i * 32) * GK + k0, &As[(i * 256 + dstg) * 8]);     \
      gload_lds16(gb0 + (size_t)(i * 32) * GK + k0, &Bs[(i * 256 + dstg) * 8]);     \
    }                                                                               \
    __syncthreads();                                                                \
    for (int kk = 0; kk < 2; kk++) {                                                \
      bf16x8 af[4], bfr[4];                                                         \
      for (int mi = 0; mi < 4; mi++) {                                              \
        const int row = wm * 64 + mi * 16 + lr;                                     \
        af[mi] = *(const bf16x8*)&As[(row * 8 + ((kk * 4 + lq) ^ (row & 7))) * 8];  \
      }                                                                             \
      for (int ni = 0; ni < 4; ni++) {                                              \
        const int row = wn * 64 + ni * 16 + lr;                                     \
        bfr[ni] = *(const bf16x8*)&Bs[(row * 8 + ((kk * 4 + lq) ^ (row & 7))) * 8]; \
      }                                                                             \
      for (int mi = 0; mi < 4; mi++)                                                \
        for (int ni = 0; ni < 4; ni++)                                              \
          acc[mi][ni] = __builtin_amdgcn_mfma_f32_16x16x32_bf16(af[mi], bfr[ni],    \
                                                                acc[mi][ni], 0, 0, 0); \
    }                                                                               \
  }

// ---------------- fused QKV GEMM: grid (8, 32, 3) ----------------
__global__ __launch_bounds__(256) void qkv_gemm(
    const __bf16* __restrict__ Xq, const __bf16* __restrict__ Xk, const __bf16* __restrict__ Xv,
    const __bf16* __restrict__ Wq, const __bf16* __restrict__ Wk, const __bf16* __restrict__ Wv,
    const float* __restrict__ bq, const float* __restrict__ bk, const float* __restrict__ bv,
    __bf16* __restrict__ Qh, __bf16* __restrict__ Kh, __bf16* __restrict__ Vt) {
  const int mode = blockIdx.z;
  const __bf16* A  = mode == 0 ? Xq : (mode == 1 ? Xk : Xv);
  const __bf16* Bw = mode == 0 ? Wq : (mode == 1 ? Wk : Wv);
  const float* bias = mode == 0 ? bq : (mode == 1 ? bk : bv);

  GEMM_BK64_BODY(A, Bw, GK)

  const int row0 = bm + wm * 64;
  const int col0 = bn + wn * 64;
  for (int ni = 0; ni < 4; ni++) {
    const int col = col0 + ni * 16 + lr;
    const float bb = bias[col];
    for (int mi = 0; mi < 4; mi++) {
      const int row = row0 + mi * 16 + lq * 4;
      if (mode == 0) {
        for (int r = 0; r < 4; r++)
          Qh[(size_t)(row + r) * GN + col] = (__bf16)((acc[mi][ni][r] + bb) * QSCALE);
      } else if (mode == 1) {
        for (int r = 0; r < 4; r++)
          Kh[(size_t)(row + r) * GN + col] = (__bf16)(acc[mi][ni][r] + bb);
      } else {
        const int b = row >> 11, s = row & 2047;
        const int h = col >> 6, d = col & 63;
        bf16x4 pk;
        for (int r = 0; r < 4; r++) pk[r] = (__bf16)(acc[mi][ni][r] + bb);
        *(bf16x4*)&Vt[(size_t)((b * CH + h) * CD + d) * CS + s] = pk;
      }
    }
  }
}

// ---------------- Wo GEMM: 64x128 tile, grid (8, 64) = 2 blocks/CU --------
// R6: previous 128x128 grid was 256 blocks = exactly 1 block/CU -> every
// per-K-step vmcnt(0)+barrier drain fully exposed (no co-resident block to
// overlap it; m114 mechanism). 64-row tiles double the grid to 512 = 2/CU.
// Same verified staging swizzle: linear gload_lds dest, source col pre-XOR'd
// by (row&7), read back with the same XOR. 4 waves as 1x4, each 64x32 out.
// Per-XCD working set: 64 wgids = 8 m-panels (1MB A) + full 2MB B < 4MB L2.
__global__ __launch_bounds__(256) void gemm_wo(const __bf16* __restrict__ Ain,
                                               const __bf16* __restrict__ Bw,
                                               const float* __restrict__ bias,
                                               float* __restrict__ O) {
  __shared__ __bf16 As[4096];
  __shared__ __bf16 Bs[8192];
  const int tid = threadIdx.x;
  const int w = tid >> 6, l = tid & 63;
  const int orig = blockIdx.y * gridDim.x + blockIdx.x;
  const int cpx = (gridDim.x * gridDim.y) >> 3;
  const int wgid = (orig & 7) * cpx + (orig >> 3);
  const int bm = (wgid / gridDim.x) * 64, bn = (wgid % gridDim.x) * 128;
  const int lr = l & 15, lq = l >> 4;
  f32x4 acc[4][2] = {};
  const int srow = w * 8 + (l >> 3);
  const int scol = ((l & 7) ^ ((l >> 3) & 7)) * 8;
  const __bf16* ga0 = Ain + (size_t)(bm + srow) * GK + scol;
  const __bf16* gb0 = Bw + (size_t)(bn + srow) * GK + scol;
  const int dstg = w * 64 + l;
  for (int k0 = 0; k0 < GK; k0 += 64) {
    __syncthreads();
    for (int i = 0; i < 2; i++)
      gload_lds16(ga0 + (size_t)(i * 32) * GK + k0, &As[(i * 256 + dstg) * 8]);
    for (int i = 0; i < 4; i++)
      gload_lds16(gb0 + (size_t)(i * 32) * GK + k0, &Bs[(i * 256 + dstg) * 8]);
    __syncthreads();
    for (int kk = 0; kk < 2; kk++) {
      bf16x8 af[4], bfr[2];
      for (int mi = 0; mi < 4; mi++) {
        const int row = mi * 16 + lr;
        af[mi] = *(const bf16x8*)&As[(row * 8 + ((kk * 4 + lq) ^ (row & 7))) * 8];
      }
      for (int ni = 0; ni < 2; ni++) {
        const int row = w * 32 + ni * 16 + lr;
        bfr[ni] = *(const bf16x8*)&Bs[(row * 8 + ((kk * 4 + lq) ^ (row & 7))) * 8];
      }
      for (int mi = 0; mi < 4; mi++)
        for (int ni = 0; ni < 2; ni++)
          acc[mi][ni] = __builtin_amdgcn_mfma_f32_16x16x32_bf16(af[mi], bfr[ni],
                                                                acc[mi][ni], 0, 0, 0);
    }
  }

  for (int ni = 0; ni < 2; ni++) {
    const int col = bn + w * 32 + ni * 16 + lr;
    const float bb = bias[col];
    for (int mi = 0; mi < 4; mi++) {
      const int row = bm + mi * 16 + lq * 4;
      for (int r = 0; r < 4; r++)
        O[(size_t)(row + r) * GN + col] = acc[mi][ni][r] + bb;
    }
  }
}

// ---------------- fused flash attention v6 (R0/R5-verified, 57.5us) ------
// 256 threads = 4 waves x 32 q-rows, 128-key tiles. S^T = K.Q^T, fast exp2,
// K=16 PV MFMA. Structural experiments R1 (dbuf+counted vmcnt), R2 (16-row
// waves / 4 blocks/CU), R3 (256-key staging) ALL regressed: 70.7 / 90.9 /
// 153.5 us vs this shape's 57.5. Do not re-attempt those axes without new
// counter evidence: R1 = intra-block pipeline adds latency at 4 waves
// (guide: 2-phase 607-682 TF < m97-structure 874-912 — only the full
// 8-phase stack wins); R2 = staging cost is per-block, more blocks = more
// traffic; R3 = 2-chunk live state spills to scratch (FETCH/WRITE +90MB).
__global__ __launch_bounds__(256, 2) void attn(const __bf16* __restrict__ Qh,
                                               const __bf16* __restrict__ Kh,
                                               const __bf16* __restrict__ Vt,
                                               __bf16* __restrict__ AO) {
  // Ks: [dchunk j 0..7][keyslot 0..127][8], keyslot = key ^ (2*(j&3))
  // Vs: [keychunk j2 0..15][dslot 0..63][8], dslot = d ^ (4*(j2&1))
  __shared__ __bf16 Ks[8192];
  __shared__ __bf16 Vs[8192];

  const int tid = threadIdx.x, w = tid >> 6, l = tid & 63;
  const int lr = l & 15, lq = l >> 4;
  const int bh = blockIdx.x;
  const int b = bh >> 4, h = bh & 15;
  const int q0 = blockIdx.y * 128 + w * 32;

  // Q as B-operand: B[n=q][k=d=kk*32+lq*8+j]  (Qh pre-scaled by QSCALE)
  bf16x8 qf[2][2];
  for (int mi = 0; mi < 2; mi++)
    for (int kk = 0; kk < 2; kk++)
      qf[mi][kk] = *(const bf16x8*)&Qh[((size_t)b * CS + q0 + mi * 16 + lr) * CE + h * CD + kk * 32 + lq * 8];

  f32x4 o[2][4] = {};
  float lsum[2] = {0.f, 0.f};
#if !PV_K16
  const bool hi_half = (lq & 1);
#endif

  for (int kt = 0; kt < CS / 128; kt++) {
    __syncthreads();
    // staging (R3-verified): K chunk j = w*2+(i>>1), half = i&1; V keychunk j2
    for (int i = 0; i < 4; i++) {
      const int j = w * 2 + (i >> 1), hf = i & 1;
      const int key = (hf * 64 + l) ^ ((j & 3) * 2);
      gload_lds16(&Kh[((size_t)b * CS + kt * 128 + key) * CE + h * CD + j * 8],
                  &Ks[(j * 128 + hf * 64) * 8]);
    }
    for (int i = 0; i < 4; i++) {
      const int j2 = w * 4 + i;
      const int d = l ^ ((j2 & 1) * 4);
      gload_lds16(&Vt[((size_t)bh * CD + d) * CS + kt * 128 + j2 * 8],
                  &Vs[(j2 * 64) * 8]);
    }
    __syncthreads();

    // S^T = K.Q^T : sa[mi][ni][r] <-> key = ni*16+lq*4+r, q = q0+mi*16+lr
    f32x4 sa[2][8] = {};
    for (int kk = 0; kk < 2; kk++) {
      bf16x8 kf[8];
      for (int ni = 0; ni < 8; ni++)
        kf[ni] = *(const bf16x8*)&Ks[((kk * 4 + lq) * 128 + ((ni * 16 + lr) ^ (lq * 2))) * 8];
      for (int mi = 0; mi < 2; mi++)
        for (int ni = 0; ni < 8; ni++)
          sa[mi][ni] = __builtin_amdgcn_mfma_f32_16x16x32_bf16(kf[ni], qf[mi][kk], sa[mi][ni], 0, 0, 0);
    }

#if PV_K16
    // exp2 + direct K=16 A-frag; V b64 frags shared across both q-halves
    for (int ni = 0; ni < 8; ni++) {
      s16x4 pa4[2];
      for (int mi = 0; mi < 2; mi++)
        for (int r = 0; r < 4; r++) {
          const float p = EXP2(sa[mi][ni][r]);
          lsum[mi] += p;
          pa4[mi][r] = bf2s((__bf16)p);
        }
      const int j2 = ni * 2 + (lq >> 1);
      const int base = j2 * 64;
      const int sw = (j2 & 1) * 4;
      for (int di = 0; di < 4; di++) {
        const int dslot = (di * 16 + lr) ^ sw;
        const s16x4 vb4 = *(const s16x4*)&Vs[(base + dslot) * 8 + (lq & 1) * 4];
        for (int mi = 0; mi < 2; mi++)
          o[mi][di] = MFMA16(pa4[mi], vb4, o[mi][di]);
      }
    }
#else
    // fallback: zero-padded K=32 PV
    for (int ni = 0; ni < 8; ni++) {
      bf16x8 pa[2];
      for (int mi = 0; mi < 2; mi++) {
        bf16x8 f;
        for (int r = 0; r < 4; r++) {
          const float p = EXP2(sa[mi][ni][r]);
          lsum[mi] += p;
          const __bf16 bv2 = (__bf16)p;
          f[r]     = hi_half ? (__bf16)0.f : bv2;
          f[4 + r] = hi_half ? bv2 : (__bf16)0.f;
        }
        pa[mi] = f;
      }
      for (int di = 0; di < 4; di++) {
        const bf16x8 vbf = *(const bf16x8*)&Vs[((ni * 2 + (lq >> 1)) * 64 + ((di * 16 + lr) ^ ((lq >> 1) * 4))) * 8];
        for (int mi = 0; mi < 2; mi++)
          o[mi][di] = __builtin_amdgcn_mfma_f32_16x16x32_bf16(pa[mi], vbf, o[mi][di], 0, 0, 0);
      }
    }
#endif
  }

  // deferred row-sum: lane partial for q = q0+mi*16+lr over keys {16ni+lq*4+r}
  for (int mi = 0; mi < 2; mi++) {
    lsum[mi] += __shfl_xor(lsum[mi], 16, 64);
    lsum[mi] += __shfl_xor(lsum[mi], 32, 64);
  }

  // o C-layout: row q_local = lq*4+r, col d = di*16+lr
  for (int mi = 0; mi < 2; mi++) {
    f32x4 rv;
    for (int r = 0; r < 4; r++) rv[r] = 1.0f / __shfl(lsum[mi], lq * 4 + r, 64);
    for (int di = 0; di < 4; di++)
      for (int r = 0; r < 4; r++) {
        const size_t s = q0 + mi * 16 + lq * 4 + r;
        AO[((size_t)b * CS + s) * CE + h * CD + di * 16 + lr] = (__bf16)(o[mi][di][r] * rv[r]);
      }
  }
}

// ---------------- launch ----------------
extern "C" void kernel_launch(void* const* d_in, const int* in_sizes, int n_in,
                              void* d_out, int out_size, void* d_ws, size_t ws_size,
                              hipStream_t stream) {
  (void)in_sizes; (void)n_in; (void)out_size; (void)ws_size;
  const float* q  = (const float*)d_in[0];
  const float* k  = (const float*)d_in[1];
  const float* v  = (const float*)d_in[2];
  const float* Wq = (const float*)d_in[3];
  const float* bq = (const float*)d_in[4];
  const float* Wk = (const float*)d_in[5];
  const float* bk = (const float*)d_in[6];
  const float* Wv = (const float*)d_in[7];
  const float* bv = (const float*)d_in[8];
  const float* Wo = (const float*)d_in[9];
  const float* bo = (const float*)d_in[10];

  __bf16* ws = (__bf16*)d_ws;
  __bf16 *Wq_b = ws + WS_WQ, *Wk_b = ws + WS_WK, *Wv_b = ws + WS_WV, *Wo_b = ws + WS_WO;
  __bf16 *Xq = ws + WS_XQ, *Xk = ws + WS_XK, *Xv = ws + WS_XV;
  __bf16 *Qh = ws + WS_QH, *Kh = ws + WS_KH, *Vt = ws + WS_VT;
  __bf16 *AO = ws + WS_AO;

  convert_all<<<8192, 256, 0, stream>>>(q, k, v, Wq, Wk, Wv, Wo, ws);

  qkv_gemm<<<dim3(GN / 128, GM / 128, 3), 256, 0, stream>>>(
      Xq, Xk, Xv, Wq_b, Wk_b, Wv_b, bq, bk, bv, Qh, Kh, Vt);

  attn<<<dim3(CB * CH, CS / 128), 256, 0, stream>>>(Qh, Kh, Vt, AO);

  gemm_wo<<<dim3(GN / 128, GM / 64), 256, 0, stream>>>(AO, Wo_b, bo, (float*)d_out);
}